// Round 7
// baseline (47.860 us; speedup 1.0000x reference)
//
#include <hip/hip_runtime.h>
#include <hip/hip_bf16.h>

typedef float f32x4 __attribute__((ext_vector_type(4)));
typedef short short8 __attribute__((ext_vector_type(8)));

constexpr int IN_F    = 4096;
constexpr int OUT_F   = 11008;
constexpr int NTILES  = OUT_F / 16;        // 688
constexpr int CHUNK_K = 256;               // 1KB int32 per row per chunk
constexpr int NCHUNK  = IN_F / CHUNK_K;    // 16
constexpr int ROWW    = 260;               // 256 + 4 pad words (1040B rows)
constexpr int NBUF    = 3;                 // LDS ring depth (2 chunks ahead)
constexpr int WAVES   = 4;

// f32 -> bf16 round-to-nearest-even
__device__ __forceinline__ unsigned short bf16_rne(float f) {
    unsigned u = __builtin_bit_cast(unsigned, f);
    u += 0x7fffu + ((u >> 16) & 1u);
    return (unsigned short)(u >> 16);
}
// int (0..126) -> bf16 exact (<= 7 significant bits)
__device__ __forceinline__ short bf16_from_int(int v) {
    float f = (float)v;
    return (short)(__builtin_bit_cast(unsigned, f) >> 16);
}

// Pre-pass: x (16x4096 f32) -> bf16 once.
__global__ __launch_bounds__(256) void cvt_x_kernel(
    const float* __restrict__ x, unsigned short* __restrict__ xb)
{
    const int i = (blockIdx.x * 256 + threadIdx.x) * 4;
    float4 v = *(const float4*)(x + i);
    ushort4 o;
    o.x = bf16_rne(v.x); o.y = bf16_rne(v.y);
    o.z = bf16_rne(v.z); o.w = bf16_rne(v.w);
    *(ushort4*)(xb + i) = o;
}

// 688 blocks x 256 threads. Deep-pipelined weight staging: 3-buffer LDS ring,
// 2 chunks prefetched ahead, counted s_waitcnt vmcnt(4) (never 0 mid-loop),
// raw s_barrier. All x fragments pre-loaded to VGPRs so the loop's vmcnt
// stream contains ONLY stage loads (exact counted waits).
__global__ __launch_bounds__(256, 3) void Int8Linear_kernel(
    const unsigned short* __restrict__ xb,  // [16][4096] bf16
    const int*   __restrict__ w,            // [11008][4096] int32 (0..126)
    const float* __restrict__ scale,        // [11008]
    const float* __restrict__ bias,         // [11008]
    float*       __restrict__ out)          // [16][11008] f32
{
    __shared__ uint32_t lds[NBUF * 16 * ROWW];   // 49,920 B -> 3 blocks/CU

    const int tid  = threadIdx.x;
    const int wave = tid >> 6;        // 0..3
    const int lane = tid & 63;
    const int m    = lane & 15;       // token row (A) / weight row in tile (B)
    const int g    = lane >> 4;       // k-subgroup
    const int n0   = blockIdx.x * 16;

    // ---- Prefetch ALL x A-fragments into registers (32 x short8 = 128 VGPR).
    // Fully unrolled -> static indices -> stays in registers (rule #20).
    short8 xf[NCHUNK][2];
    #pragma unroll
    for (int c = 0; c < NCHUNK; ++c) {
        #pragma unroll
        for (int s = 0; s < 2; ++s) {
            const int k0 = c * CHUNK_K + (wave * 2 + s) * 32;
            xf[c][s] = *(const short8*)(xb + (size_t)m * IN_F + k0 + g * 8);
        }
    }

    // Stage chunk c: 16 rows x 1KB; wave v loads rows 4v..4v+3, each one
    // wave-contiguous global_load_lds (lane i -> base + i*16B).
    auto stage = [&](int c) {
        const int buf = (c % NBUF) * 16 * ROWW;
        #pragma unroll
        for (int r = 0; r < 4; ++r) {
            const int row = wave * 4 + r;
            const int* gp = w + (size_t)(n0 + row) * IN_F + c * CHUNK_K + lane * 4;
            __builtin_amdgcn_global_load_lds(
                (const __attribute__((address_space(1))) uint32_t*)gp,
                (__attribute__((address_space(3))) uint32_t*)&lds[buf + row * ROWW + lane * 4],
                16, 0, 0);
        }
    };

    f32x4 acc = {0.f, 0.f, 0.f, 0.f};

    stage(0);                                   // 4 loads
    stage(1);                                   // 4 loads
    asm volatile("s_waitcnt vmcnt(8)" ::: "memory");   // all 32 x-loads done

    #pragma unroll
    for (int c = 0; c < NCHUNK; ++c) {
        // Counted wait: chunks c+1 (and c+2 once issued) stay in flight.
        if (c < NCHUNK - 1) asm volatile("s_waitcnt vmcnt(4)" ::: "memory");
        else                asm volatile("s_waitcnt vmcnt(0)" ::: "memory");
        __builtin_amdgcn_s_barrier();
        asm volatile("" ::: "memory");

        const int buf = (c % NBUF) * 16 * ROWW;
        #pragma unroll
        for (int s = 0; s < 2; ++s) {
            const int kc = (wave * 2 + s) * 32;
            const uint32_t* bw = &lds[buf + m * ROWW + kc + g * 8];
            int4 wa = *(const int4*)bw;
            int4 wb = *(const int4*)(bw + 4);

            short8 b;
            b[0] = bf16_from_int(wa.x); b[1] = bf16_from_int(wa.y);
            b[2] = bf16_from_int(wa.z); b[3] = bf16_from_int(wa.w);
            b[4] = bf16_from_int(wb.x); b[5] = bf16_from_int(wb.y);
            b[6] = bf16_from_int(wb.z); b[7] = bf16_from_int(wb.w);

            acc = __builtin_amdgcn_mfma_f32_16x16x32_bf16(xf[c][s], b, acc, 0, 0, 0);
        }

        // Issue next prefetch AFTER compute: overwrites buf[(c-1)%3], which
        // every wave finished before this iteration's barrier.
        if (c + 2 < NCHUNK) stage(c + 2);
    }

    // Cross-wave K reduction (reuse LDS), fused scale+bias epilogue.
    __syncthreads();
    float* red = (float*)lds;   // [4][16][16] f32
    #pragma unroll
    for (int r = 0; r < 4; ++r)
        red[(wave * 16 + g * 4 + r) * 16 + m] = acc[r];
    __syncthreads();

    const int row = tid >> 4;   // token
    const int col = tid & 15;
    float s = 0.f;
    #pragma unroll
    for (int v = 0; v < WAVES; ++v)
        s += red[(v * 16 + row) * 16 + col];
    const int o = n0 + col;
    out[(size_t)row * OUT_F + o] = s * scale[o] + bias[o];
}

extern "C" void kernel_launch(void* const* d_in, const int* in_sizes, int n_in,
                              void* d_out, int out_size, void* d_ws, size_t ws_size,
                              hipStream_t stream) {
    const float* x     = (const float*)d_in[0];
    const int*   w     = (const int*)d_in[1];
    const float* scale = (const float*)d_in[2];
    const float* bias  = (const float*)d_in[3];
    float*       out   = (float*)d_out;
    unsigned short* xb = (unsigned short*)d_ws;   // 128 KB

    cvt_x_kernel<<<64, 256, 0, stream>>>(x, xb);
    Int8Linear_kernel<<<NTILES, 256, 0, stream>>>(xb, w, scale, bias, out);
}